// Round 15
// baseline (279.217 us; speedup 1.0000x reference)
//
#include <hip/hip_runtime.h>
#include <hip/hip_bf16.h>
#include <cstdint>

typedef __bf16 bf16x8 __attribute__((ext_vector_type(8)));
typedef float  f32x4  __attribute__((ext_vector_type(4)));

// ================= graph build: two-level counting sort =================

__global__ __launch_bounds__(256) void bucket_hist_kernel(const int* __restrict__ dst,
                                                          int* __restrict__ bhist,
                                                          int E, int NBK, int shift) {
    __shared__ int lh[1024];
    int t = threadIdx.x;
    for (int i = t; i < 1024; i += 256) lh[i] = 0;
    __syncthreads();
#pragma unroll
    for (int v = 0; v < 4; ++v) {
        int idx = blockIdx.x * 4096 + (v * 256 + t) * 4;
        if (idx + 3 < E) {
            int4 d = *reinterpret_cast<const int4*>(&dst[idx]);
            atomicAdd(&lh[d.x >> shift], 1);
            atomicAdd(&lh[d.y >> shift], 1);
            atomicAdd(&lh[d.z >> shift], 1);
            atomicAdd(&lh[d.w >> shift], 1);
        } else {
            for (int k = 0; k < 4; ++k)
                if (idx + k < E) atomicAdd(&lh[dst[idx + k] >> shift], 1);
        }
    }
    __syncthreads();
    for (int i = t; i < NBK; i += 256)
        if (lh[i]) atomicAdd(&bhist[i], lh[i]);
}

__global__ __launch_bounds__(256) void bucket_scan_kernel(const int* __restrict__ bhist,
                                                          int* __restrict__ bbase,
                                                          int* __restrict__ bcur,
                                                          int NBK, int* __restrict__ offsetsN, int E) {
    int t = threadIdx.x;
    int v0[4]; int s = 0;
#pragma unroll
    for (int k = 0; k < 4; ++k) { int i = t * 4 + k; v0[k] = (i < NBK) ? bhist[i] : 0; s += v0[k]; }
    int lane = t & 63, w = t >> 6;
    int v = s;
#pragma unroll
    for (int o = 1; o < 64; o <<= 1) { int u = __shfl_up(v, o); if (lane >= o) v += u; }
    __shared__ int ws[4];
    if (lane == 63) ws[w] = v;
    __syncthreads();
    if (t == 0) { int r = 0; for (int i = 0; i < 4; ++i) { int x = ws[i]; ws[i] = r; r += x; } }
    __syncthreads();
    int run = ws[w] + (v - s);
#pragma unroll
    for (int k = 0; k < 4; ++k) {
        int i = t * 4 + k;
        if (i < NBK) { bbase[i] = run; bcur[i] = run; run += v0[k]; }
    }
    if (t == 255) bbase[NBK] = E;
    if (t == 0)   *offsetsN = E;
}

// binned entry: (src << shift) | local_dst
__global__ __launch_bounds__(256) void bin_edges_kernel(const int* __restrict__ src,
                                                        const int* __restrict__ dst,
                                                        int* __restrict__ bcur,
                                                        unsigned* __restrict__ binned,
                                                        int E, int NBK, int shift) {
    __shared__ int lh[1024];
    int t = threadIdx.x;
    int mask = (1 << shift) - 1;
    for (int i = t; i < 1024; i += 256) lh[i] = 0;
    __syncthreads();
    int sv[32], dv[32], rk[32];
#pragma unroll
    for (int v = 0; v < 8; ++v) {
        int idx = blockIdx.x * 8192 + (v * 256 + t) * 4;
        if (idx + 3 < E) {
            int4 s4 = *reinterpret_cast<const int4*>(&src[idx]);
            int4 d4 = *reinterpret_cast<const int4*>(&dst[idx]);
            sv[v * 4 + 0] = s4.x; sv[v * 4 + 1] = s4.y; sv[v * 4 + 2] = s4.z; sv[v * 4 + 3] = s4.w;
            dv[v * 4 + 0] = d4.x; dv[v * 4 + 1] = d4.y; dv[v * 4 + 2] = d4.z; dv[v * 4 + 3] = d4.w;
        } else {
            for (int k = 0; k < 4; ++k) {
                sv[v * 4 + k] = (idx + k < E) ? src[idx + k] : 0;
                dv[v * 4 + k] = (idx + k < E) ? dst[idx + k] : -1;
            }
        }
    }
#pragma unroll
    for (int k = 0; k < 32; ++k)
        if (dv[k] >= 0) rk[k] = atomicAdd(&lh[dv[k] >> shift], 1);
    __syncthreads();
    for (int i = t; i < NBK; i += 256) {
        int c = lh[i];
        lh[i] = c ? atomicAdd(&bcur[i], c) : 0;
    }
    __syncthreads();
#pragma unroll
    for (int k = 0; k < 32; ++k) {
        if (dv[k] >= 0) {
            int b = dv[k] >> shift;
            binned[lh[b] + rk[k]] = ((unsigned)sv[k] << shift) | (unsigned)(dv[k] & mask);
        }
    }
}

__global__ __launch_bounds__(256) void bucket_build_kernel(const unsigned* __restrict__ binned,
                                                           const int* __restrict__ bbase,
                                                           int* __restrict__ csr_src,
                                                           int* __restrict__ offsets,
                                                           float* __restrict__ dinv,
                                                           int N, int shift) {
    int b = blockIdx.x;
    int t = threadIdx.x;
    int node0 = b << shift;
    int npb = min(1 << shift, N - node0);
    int bb = bbase[b], be = bbase[b + 1];
    int mask = (1 << shift) - 1;
    __shared__ int ncnt[256], npre[256], ncur[256];
    ncnt[t] = 0;
    __syncthreads();
    for (int e = bb + t; e < be; e += 256) {
        unsigned p = binned[e];
        atomicAdd(&ncnt[p & mask], 1);
    }
    __syncthreads();
    int deg = (t < npb) ? ncnt[t] : 0;
    int v = deg;
    int lane = t & 63, w = t >> 6;
#pragma unroll
    for (int o = 1; o < 64; o <<= 1) { int u = __shfl_up(v, o); if (lane >= o) v += u; }
    __shared__ int ws[4];
    if (lane == 63) ws[w] = v;
    __syncthreads();
    if (t == 0) { int r = 0; for (int i = 0; i < 4; ++i) { int x = ws[i]; ws[i] = r; r += x; } }
    __syncthreads();
    int pre = bb + ws[w] + v - deg;
    npre[t] = pre; ncur[t] = 0;
    __syncthreads();
    for (int e = bb + t; e < be; e += 256) {
        unsigned p = binned[e];
        int l = p & mask;
        int r = atomicAdd(&ncur[l], 1);
        csr_src[npre[l] + r] = (int)(p >> shift);
    }
    if (t < npb) {
        int node = node0 + t;
        offsets[node] = pre;
        dinv[node] = rsqrtf((float)(deg + 1));
    }
}

// ---------------- weight prep: Wf = W1@encW (f32), bf = W1@encb; cvt all to bf16 ----------------
__global__ __launch_bounds__(128) void prep_weights_kernel(const float* __restrict__ W1,
                                                           const float* __restrict__ encW,
                                                           const float* __restrict__ encb,
                                                           const float* __restrict__ W2,
                                                           const float* __restrict__ decW,
                                                           __hip_bfloat16* __restrict__ Wfb,
                                                           float* __restrict__ bff,
                                                           __hip_bfloat16* __restrict__ W2b,
                                                           __hip_bfloat16* __restrict__ decWb) {
    int i = blockIdx.x;
    int j = threadIdx.x;
    const float* w1r = W1 + (size_t)i * 128;
    float s0 = 0.f, s1 = 0.f, s2 = 0.f, s3 = 0.f;
    for (int k = 0; k < 128; k += 4) {
        s0 += w1r[k + 0] * encW[(size_t)(k + 0) * 128 + j];
        s1 += w1r[k + 1] * encW[(size_t)(k + 1) * 128 + j];
        s2 += w1r[k + 2] * encW[(size_t)(k + 2) * 128 + j];
        s3 += w1r[k + 3] * encW[(size_t)(k + 3) * 128 + j];
    }
    Wfb[(size_t)i * 128 + j] = __float2bfloat16((s0 + s1) + (s2 + s3));
    W2b[(size_t)i * 128 + j] = __float2bfloat16(W2[(size_t)i * 128 + j]);
    if (i < 48) decWb[(size_t)i * 128 + j] = __float2bfloat16(i < 40 ? decW[(size_t)i * 128 + j] : 0.f);
    float t = w1r[j] * encb[j];
#pragma unroll
    for (int o = 32; o; o >>= 1) t += __shfl_down(t, o);
    __shared__ float red[2];
    if ((j & 63) == 0) red[j >> 6] = t;
    __syncthreads();
    if (j == 0) bff[i] = red[0] + red[1];
}

__device__ inline bf16x8 cvt8(float4 lo, float4 hi) {
    union { unsigned short u[8]; bf16x8 v; } t;
    t.u[0] = __builtin_bit_cast(unsigned short, __float2bfloat16(lo.x));
    t.u[1] = __builtin_bit_cast(unsigned short, __float2bfloat16(lo.y));
    t.u[2] = __builtin_bit_cast(unsigned short, __float2bfloat16(lo.z));
    t.u[3] = __builtin_bit_cast(unsigned short, __float2bfloat16(lo.w));
    t.u[4] = __builtin_bit_cast(unsigned short, __float2bfloat16(hi.x));
    t.u[5] = __builtin_bit_cast(unsigned short, __float2bfloat16(hi.y));
    t.u[6] = __builtin_bit_cast(unsigned short, __float2bfloat16(hi.z));
    t.u[7] = __builtin_bit_cast(unsigned short, __float2bfloat16(hi.w));
    return t.v;
}

// ---------------- encoder GEMM: hb = dinv[r]*(X @ Wf^T + bf), row-major bf16 out ----------------
__global__ __launch_bounds__(256) void gemm_enc_kernel(const float* __restrict__ Ain,
                                                       const __hip_bfloat16* __restrict__ W,
                                                       const float* __restrict__ bias,
                                                       const float* __restrict__ dscale,
                                                       __hip_bfloat16* __restrict__ out, int M) {
    int lane = threadIdx.x & 63;
    int wave = threadIdx.x >> 6;
    int row0 = blockIdx.x * 128 + wave * 32;
    int kgrp = lane >> 4, cl = lane & 15;

    bf16x8 afrag[2][4];
#pragma unroll
    for (int rt = 0; rt < 2; ++rt) {
        int ar = row0 + rt * 16 + cl;
        if (ar >= M) ar = M - 1;
        const float* Ar = Ain + (size_t)ar * 128;
#pragma unroll
        for (int c = 0; c < 4; ++c) {
            const float4* q = reinterpret_cast<const float4*>(Ar + (4 * c + kgrp) * 8);
            afrag[rt][c] = cvt8(q[0], q[1]);
        }
    }

    f32x4 acc[2][8];
#pragma unroll
    for (int rt = 0; rt < 2; ++rt)
#pragma unroll
        for (int t = 0; t < 8; ++t) acc[rt][t] = {0.f, 0.f, 0.f, 0.f};

#pragma unroll
    for (int c = 0; c < 4; ++c) {
#pragma unroll
        for (int t = 0; t < 8; ++t) {
            bf16x8 bfrag = reinterpret_cast<const bf16x8*>(W + (size_t)(t * 16 + cl) * 128)[4 * c + kgrp];
            acc[0][t] = __builtin_amdgcn_mfma_f32_16x16x32_bf16(afrag[0][c], bfrag, acc[0][t], 0, 0, 0);
            acc[1][t] = __builtin_amdgcn_mfma_f32_16x16x32_bf16(afrag[1][c], bfrag, acc[1][t], 0, 0, 0);
        }
    }

#pragma unroll
    for (int rt = 0; rt < 2; ++rt) {
        int rbase = row0 + rt * 16 + kgrp * 4;
#pragma unroll
        for (int i = 0; i < 4; ++i) {
            int r = rbase + i;
            float sc = dscale[(r < M) ? r : (M - 1)];
#pragma unroll
            for (int t = 0; t < 8; ++t) {
                int col = t * 16 + cl;
                float v = (acc[rt][t][i] + bias[col]) * sc;
                unsigned int uv = __builtin_bit_cast(unsigned short, __float2bfloat16(v));
                unsigned int pv = (unsigned int)__shfl_xor((int)uv, 1);
                if (!(lane & 1) && r < M)
                    *reinterpret_cast<unsigned int*>(out + (size_t)r * 128 + col) = (uv & 0xffffu) | (pv << 16);
            }
        }
    }
}

// ---------------- single-wave pipelined agg phase: 4 nodes per wave/block ----------------
// csr padded with >=8 zero entries past E. All 4 self-rows + first csr batches issue
// in the prologue; node i+1's 8 row-loads issue before node i's accumulation.
// LDS u32 index: row*64 + (lane ^ (row<<2)), rows 0..3.
__device__ __forceinline__ void agg_phase4(const __hip_bfloat16* __restrict__ h,
                                           const int* __restrict__ csr,
                                           const int* __restrict__ offsets,
                                           const float* __restrict__ dinv,
                                           const float* __restrict__ bias,
                                           unsigned* lds, int base, int N) {
    int lane = threadIdx.x & 63;
    int bc = lane * 2;
    float2 bb = *reinterpret_cast<const float2*>(&bias[bc]);
    int oidx = base + (lane < 4 ? lane : 4);
    if (oidx > N) oidx = N;
    int off = offsets[oidx];                     // one coalesced load, 5 lanes useful

    int j0a[4], dga[4], nda[4];
    unsigned qs[4];
#pragma unroll
    for (int i = 0; i < 4; ++i) {
        int node = base + i;
        nda[i] = __builtin_amdgcn_readfirstlane((node < N) ? node : (N - 1));
        j0a[i] = __builtin_amdgcn_readfirstlane(__shfl(off, i));
        int j1 = __builtin_amdgcn_readfirstlane(__shfl(off, i + 1));
        dga[i] = j1 - j0a[i];                    // 0 for dead nodes
        qs[i] = *reinterpret_cast<const unsigned*>(&h[(size_t)nda[i] * 128 + bc]);  // self row
    }
    // prefetch first csr batch of every node (uniform -> s_loads; pad makes it safe)
    int sc[4][8];
#pragma unroll
    for (int i = 0; i < 4; ++i)
#pragma unroll
        for (int k = 0; k < 8; ++k)
            sc[i][k] = csr[j0a[i] + k];
    // prime node 0's first-batch row loads
    unsigned qn[8];
#pragma unroll
    for (int k = 0; k < 8; ++k)
        qn[k] = *reinterpret_cast<const unsigned*>(&h[(size_t)sc[0][k] * 128 + bc]);

#pragma unroll
    for (int i = 0; i < 4; ++i) {
        int j0 = j0a[i], dg = dga[i];
        bool live = (base + i) < N;

        unsigned qc[8];
#pragma unroll
        for (int k = 0; k < 8; ++k) qc[k] = qn[k];
        if (i + 1 < 4) {                         // issue next node's first batch NOW
#pragma unroll
            for (int k = 0; k < 8; ++k)
                qn[k] = *reinterpret_cast<const unsigned*>(&h[(size_t)sc[i + 1][k] * 128 + bc]);
        }

        float ax[8], ay[8];
        ax[0] = __builtin_bit_cast(float, qs[i] << 16);
        ay[0] = __builtin_bit_cast(float, qs[i] & 0xffff0000u);
#pragma unroll
        for (int k = 1; k < 8; ++k) { ax[k] = 0.f; ay[k] = 0.f; }

        // batch 0 (masked; dg uniform)
#pragma unroll
        for (int k = 0; k < 8; ++k) {
            unsigned q = (k < dg) ? qc[k] : 0u;
            ax[k] += __builtin_bit_cast(float, q << 16);
            ay[k] += __builtin_bit_cast(float, q & 0xffff0000u);
        }
        // batches 1..nb-1
        int nb = (dg + 7) >> 3;
        for (int b = 1; b < nb; ++b) {
            int jb = j0 + 8 * b;
            int s[8];
#pragma unroll
            for (int k = 0; k < 8; ++k) s[k] = csr[jb + k];
            unsigned q[8];
#pragma unroll
            for (int k = 0; k < 8; ++k)
                q[k] = *reinterpret_cast<const unsigned*>(&h[(size_t)s[k] * 128 + bc]);
            int rem = dg - 8 * b;
#pragma unroll
            for (int k = 0; k < 8; ++k) {
                unsigned qq = (k < rem) ? q[k] : 0u;
                ax[k] += __builtin_bit_cast(float, qq << 16);
                ay[k] += __builtin_bit_cast(float, qq & 0xffff0000u);
            }
        }

        float sx = ((ax[0] + ax[1]) + (ax[2] + ax[3])) + ((ax[4] + ax[5]) + (ax[6] + ax[7]));
        float sy = ((ay[0] + ay[1]) + (ay[2] + ay[3])) + ((ay[4] + ay[5]) + (ay[6] + ay[7]));
        float dd = dinv[nda[i]];
        float ox = fmaxf(dd * sx + bb.x, 0.f);
        float oy = fmaxf(dd * sy + bb.y, 0.f);
        unsigned ow = (unsigned)__builtin_bit_cast(unsigned short, __float2bfloat16(ox)) |
                      ((unsigned)__builtin_bit_cast(unsigned short, __float2bfloat16(oy)) << 16);
        if (!live) ow = 0u;
        lds[i * 64 + (lane ^ (i << 2))] = ow;
    }
}

// ---------------- fused agg1 + conv2 GEMM: 1 wave / 4 nodes, no inter-wave barrier ----------------
// A-fragment rows 0-3 = this wave's nodes (rows 4-15 read duplicates; matmul is
// row-independent). __syncthreads over a single wave is just a waitcnt - free.
__global__ __launch_bounds__(64, 8) void agg_gemm_kernel(const __hip_bfloat16* __restrict__ h,
                                                         const int* __restrict__ csr,
                                                         const int* __restrict__ offsets,
                                                         const float* __restrict__ dinv,
                                                         const float* __restrict__ bias,
                                                         const __hip_bfloat16* __restrict__ W,
                                                         __hip_bfloat16* __restrict__ out, int N) {
    __shared__ unsigned lds[4 * 64];
    int base = blockIdx.x * 4;
    agg_phase4(h, csr, offsets, dinv, bias, lds, base, N);
    __syncthreads();

    int lane = threadIdx.x & 63;
    int kgrp = lane >> 4, cl = lane & 15;
    int row = cl & 3;                             // duplicate rows 0-3 across cl 4-15
    bf16x8 afrag[4];
#pragma unroll
    for (int c = 0; c < 4; ++c) {
        int kk = 4 * c + kgrp;
        afrag[c] = *reinterpret_cast<const bf16x8*>(&lds[row * 64 + ((kk * 4) ^ (row << 2))]);
    }
    float sc4[4];
#pragma unroll
    for (int i = 0; i < 4; ++i) sc4[i] = dinv[min(base + i, N - 1)];

#pragma unroll
    for (int t = 0; t < 8; ++t) {
        f32x4 acc = {0.f, 0.f, 0.f, 0.f};
#pragma unroll
        for (int c = 0; c < 4; ++c) {
            bf16x8 bfrag = reinterpret_cast<const bf16x8*>(W + (size_t)(t * 16 + cl) * 128)[4 * c + kgrp];
            acc = __builtin_amdgcn_mfma_f32_16x16x32_bf16(afrag[c], bfrag, acc, 0, 0, 0);
        }
#pragma unroll
        for (int i = 0; i < 4; ++i) {            // C rows 0-3 live in lanes 0-15 (kgrp 0)
            float v = acc[i] * sc4[i];
            unsigned uv = __builtin_bit_cast(unsigned short, __float2bfloat16(v));
            unsigned pv = (unsigned)__shfl_xor((int)uv, 1);
            if (!(lane & 1) && lane < 16 && base + i < N)
                *reinterpret_cast<unsigned*>(out + (size_t)(base + i) * 128 + t * 16 + cl) =
                    (uv & 0xffffu) | (pv << 16);
        }
    }
}

// ---------------- fused agg2 + decoder GEMM + log_softmax: 1 wave / 4 nodes ----------------
__global__ __launch_bounds__(64, 8) void agg_dec_kernel(const __hip_bfloat16* __restrict__ h,
                                                        const int* __restrict__ csr,
                                                        const int* __restrict__ offsets,
                                                        const float* __restrict__ dinv,
                                                        const float* __restrict__ bias,
                                                        const __hip_bfloat16* __restrict__ Wd,
                                                        const float* __restrict__ bd,
                                                        float* __restrict__ out, int N) {
    __shared__ unsigned lds[4 * 64];
    int base = blockIdx.x * 4;
    agg_phase4(h, csr, offsets, dinv, bias, lds, base, N);
    __syncthreads();

    int lane = threadIdx.x & 63;
    int kgrp = lane >> 4, cl = lane & 15;
    int row = cl & 3;
    bf16x8 afrag[4];
#pragma unroll
    for (int c = 0; c < 4; ++c) {
        int kk = 4 * c + kgrp;
        afrag[c] = *reinterpret_cast<const bf16x8*>(&lds[row * 64 + ((kk * 4) ^ (row << 2))]);
    }
    f32x4 acc[3];
#pragma unroll
    for (int t = 0; t < 3; ++t) acc[t] = {0.f, 0.f, 0.f, 0.f};
#pragma unroll
    for (int c = 0; c < 4; ++c)
#pragma unroll
        for (int t = 0; t < 3; ++t) {
            bf16x8 bfrag = reinterpret_cast<const bf16x8*>(Wd + (size_t)(t * 16 + cl) * 128)[4 * c + kgrp];
            acc[t] = __builtin_amdgcn_mfma_f32_16x16x32_bf16(afrag[c], bfrag, acc[t], 0, 0, 0);
        }

    float v[3][4];
#pragma unroll
    for (int t = 0; t < 3; ++t) {
        int col = t * 16 + cl;
        float bv = (col < 40) ? bd[col] : 0.f;
#pragma unroll
        for (int i = 0; i < 4; ++i)
            v[t][i] = (col < 40) ? (acc[t][i] + bv) : -INFINITY;
    }
#pragma unroll
    for (int i = 0; i < 4; ++i) {                 // rows 0-3 live in lanes 0-15
        float m = fmaxf(fmaxf(v[0][i], v[1][i]), v[2][i]);
#pragma unroll
        for (int o = 1; o < 16; o <<= 1) m = fmaxf(m, __shfl_xor(m, o));
        float s = 0.f;
#pragma unroll
        for (int t = 0; t < 3; ++t) s += (v[t][i] > -INFINITY) ? __expf(v[t][i] - m) : 0.f;
#pragma unroll
        for (int o = 1; o < 16; o <<= 1) s += __shfl_xor(s, o);
        float lse = __logf(s);
        int r = base + i;
        if (lane < 16 && r < N) {
#pragma unroll
            for (int t = 0; t < 3; ++t) {
                int col = t * 16 + cl;
                if (col < 40) out[(size_t)r * 40 + col] = v[t][i] - m - lse;
            }
        }
    }
}

extern "C" void kernel_launch(void* const* d_in, const int* in_sizes, int n_in,
                              void* d_out, int out_size, void* d_ws, size_t ws_size,
                              hipStream_t stream) {
    const float* X    = (const float*)d_in[0];
    const int*   ei   = (const int*)d_in[1];
    const float* encW = (const float*)d_in[2];
    const float* encb = (const float*)d_in[3];
    const float* W1   = (const float*)d_in[4];
    const float* b1   = (const float*)d_in[5];
    const float* W2   = (const float*)d_in[6];
    const float* b2   = (const float*)d_in[7];
    const float* decW = (const float*)d_in[8];
    const float* decb = (const float*)d_in[9];

    const int N = in_sizes[0] / 128;
    const int E = in_sizes[1] / 2;
    const int* src = ei;
    const int* dst = ei + E;

    int shift = 7;
    while ((((N - 1) >> shift) + 1) > 1024) ++shift;
    const int NBK = ((N - 1) >> shift) + 1;

    uint8_t* p = (uint8_t*)d_ws;
    auto carve = [&](size_t bytes) -> void* {
        uint8_t* r = p;
        p += (bytes + 255) & ~(size_t)255;
        return (void*)r;
    };
    int*   offsets = (int*)carve((size_t)(N + 1) * 4);
    float* dinv    = (float*)carve((size_t)N * 4);
    int*   bhist   = (int*)carve(1025 * 4);
    int*   bbase   = (int*)carve(1025 * 4);
    int*   bcur    = (int*)carve(1024 * 4);
    int*   csr_src = (int*)carve(((size_t)E + 16) * 4);  // zero pad for batch prefetch
    __hip_bfloat16* Wfb   = (__hip_bfloat16*)carve(16384 * 2);
    __hip_bfloat16* W2b   = (__hip_bfloat16*)carve(16384 * 2);
    __hip_bfloat16* decWb = (__hip_bfloat16*)carve(48 * 128 * 2);
    float*          bff   = (float*)carve(128 * 4);
    __hip_bfloat16* xb    = (__hip_bfloat16*)carve((size_t)N * 128 * 2);
    __hip_bfloat16* hb    = (__hip_bfloat16*)carve((size_t)N * 128 * 2);
    unsigned* binned = (unsigned*)xb;   // dead before xb is first written (by agg_gemm)

    // --- weight prep (independent of graph) ---
    prep_weights_kernel<<<128, 128, 0, stream>>>(W1, encW, encb, W2, decW, Wfb, bff, W2b, decWb);

    // --- graph structure ---
    hipMemsetAsync(bhist, 0, (size_t)NBK * 4, stream);
    hipMemsetAsync(csr_src + E, 0, 16 * 4, stream);      // zero the prefetch pad
    bucket_hist_kernel<<<(E + 4095) / 4096, 256, 0, stream>>>(dst, bhist, E, NBK, shift);
    bucket_scan_kernel<<<1, 256, 0, stream>>>(bhist, bbase, bcur, NBK, &offsets[N], E);
    bin_edges_kernel<<<(E + 8191) / 8192, 256, 0, stream>>>(src, dst, bcur, binned, E, NBK, shift);
    bucket_build_kernel<<<NBK, 256, 0, stream>>>(binned, bbase, csr_src, offsets, dinv, N, shift);

    int gblocks = (N + 127) / 128;
    int tblocks = (N + 3) / 4;
    // fused encoder+conv1 linear: hb = dinv[r] * (X @ Wf^T + bf)
    gemm_enc_kernel<<<gblocks, 256, 0, stream>>>(X, Wfb, bff, dinv, hb, N);
    // agg1 (+b1, relu) fused with conv2 linear: xb = dinv[r] * (agg(hb) @ W2^T)
    agg_gemm_kernel<<<tblocks, 64, 0, stream>>>(hb, csr_src, offsets, dinv, b1, W2b, xb, N);
    // agg2 (+b2, relu) fused with decoder + log_softmax
    agg_dec_kernel<<<tblocks, 64, 0, stream>>>(xb, csr_src, offsets, dinv, b2, decWb, decb,
                                               (float*)d_out, N);
}

// Round 16
// 225.108 us; speedup vs baseline: 1.2404x; 1.2404x over previous
//
#include <hip/hip_runtime.h>
#include <hip/hip_bf16.h>
#include <cstdint>

typedef __bf16 bf16x8 __attribute__((ext_vector_type(8)));
typedef float  f32x4  __attribute__((ext_vector_type(4)));

// ================= graph build: two-level counting sort =================

__global__ __launch_bounds__(256) void bucket_hist_kernel(const int* __restrict__ dst,
                                                          int* __restrict__ bhist,
                                                          int E, int NBK, int shift) {
    __shared__ int lh[1024];
    int t = threadIdx.x;
    for (int i = t; i < 1024; i += 256) lh[i] = 0;
    __syncthreads();
#pragma unroll
    for (int v = 0; v < 4; ++v) {
        int idx = blockIdx.x * 4096 + (v * 256 + t) * 4;
        if (idx + 3 < E) {
            int4 d = *reinterpret_cast<const int4*>(&dst[idx]);
            atomicAdd(&lh[d.x >> shift], 1);
            atomicAdd(&lh[d.y >> shift], 1);
            atomicAdd(&lh[d.z >> shift], 1);
            atomicAdd(&lh[d.w >> shift], 1);
        } else {
            for (int k = 0; k < 4; ++k)
                if (idx + k < E) atomicAdd(&lh[dst[idx + k] >> shift], 1);
        }
    }
    __syncthreads();
    for (int i = t; i < NBK; i += 256)
        if (lh[i]) atomicAdd(&bhist[i], lh[i]);
}

__global__ __launch_bounds__(256) void bucket_scan_kernel(const int* __restrict__ bhist,
                                                          int* __restrict__ bbase,
                                                          int* __restrict__ bcur,
                                                          int NBK, int* __restrict__ offsetsN, int E) {
    int t = threadIdx.x;
    int v0[4]; int s = 0;
#pragma unroll
    for (int k = 0; k < 4; ++k) { int i = t * 4 + k; v0[k] = (i < NBK) ? bhist[i] : 0; s += v0[k]; }
    int lane = t & 63, w = t >> 6;
    int v = s;
#pragma unroll
    for (int o = 1; o < 64; o <<= 1) { int u = __shfl_up(v, o); if (lane >= o) v += u; }
    __shared__ int ws[4];
    if (lane == 63) ws[w] = v;
    __syncthreads();
    if (t == 0) { int r = 0; for (int i = 0; i < 4; ++i) { int x = ws[i]; ws[i] = r; r += x; } }
    __syncthreads();
    int run = ws[w] + (v - s);
#pragma unroll
    for (int k = 0; k < 4; ++k) {
        int i = t * 4 + k;
        if (i < NBK) { bbase[i] = run; bcur[i] = run; run += v0[k]; }
    }
    if (t == 255) bbase[NBK] = E;
    if (t == 0)   *offsetsN = E;
}

// binned entry: (src << shift) | local_dst
__global__ __launch_bounds__(256) void bin_edges_kernel(const int* __restrict__ src,
                                                        const int* __restrict__ dst,
                                                        int* __restrict__ bcur,
                                                        unsigned* __restrict__ binned,
                                                        int E, int NBK, int shift) {
    __shared__ int lh[1024];
    int t = threadIdx.x;
    int mask = (1 << shift) - 1;
    for (int i = t; i < 1024; i += 256) lh[i] = 0;
    __syncthreads();
    int sv[32], dv[32], rk[32];
#pragma unroll
    for (int v = 0; v < 8; ++v) {
        int idx = blockIdx.x * 8192 + (v * 256 + t) * 4;
        if (idx + 3 < E) {
            int4 s4 = *reinterpret_cast<const int4*>(&src[idx]);
            int4 d4 = *reinterpret_cast<const int4*>(&dst[idx]);
            sv[v * 4 + 0] = s4.x; sv[v * 4 + 1] = s4.y; sv[v * 4 + 2] = s4.z; sv[v * 4 + 3] = s4.w;
            dv[v * 4 + 0] = d4.x; dv[v * 4 + 1] = d4.y; dv[v * 4 + 2] = d4.z; dv[v * 4 + 3] = d4.w;
        } else {
            for (int k = 0; k < 4; ++k) {
                sv[v * 4 + k] = (idx + k < E) ? src[idx + k] : 0;
                dv[v * 4 + k] = (idx + k < E) ? dst[idx + k] : -1;
            }
        }
    }
#pragma unroll
    for (int k = 0; k < 32; ++k)
        if (dv[k] >= 0) rk[k] = atomicAdd(&lh[dv[k] >> shift], 1);
    __syncthreads();
    for (int i = t; i < NBK; i += 256) {
        int c = lh[i];
        lh[i] = c ? atomicAdd(&bcur[i], c) : 0;
    }
    __syncthreads();
#pragma unroll
    for (int k = 0; k < 32; ++k) {
        if (dv[k] >= 0) {
            int b = dv[k] >> shift;
            binned[lh[b] + rk[k]] = ((unsigned)sv[k] << shift) | (unsigned)(dv[k] & mask);
        }
    }
}

__global__ __launch_bounds__(256) void bucket_build_kernel(const unsigned* __restrict__ binned,
                                                           const int* __restrict__ bbase,
                                                           int* __restrict__ csr_src,
                                                           int* __restrict__ offsets,
                                                           float* __restrict__ dinv,
                                                           int N, int shift) {
    int b = blockIdx.x;
    int t = threadIdx.x;
    int node0 = b << shift;
    int npb = min(1 << shift, N - node0);
    int bb = bbase[b], be = bbase[b + 1];
    int mask = (1 << shift) - 1;
    __shared__ int ncnt[256], npre[256], ncur[256];
    ncnt[t] = 0;
    __syncthreads();
    for (int e = bb + t; e < be; e += 256) {
        unsigned p = binned[e];
        atomicAdd(&ncnt[p & mask], 1);
    }
    __syncthreads();
    int deg = (t < npb) ? ncnt[t] : 0;
    int v = deg;
    int lane = t & 63, w = t >> 6;
#pragma unroll
    for (int o = 1; o < 64; o <<= 1) { int u = __shfl_up(v, o); if (lane >= o) v += u; }
    __shared__ int ws[4];
    if (lane == 63) ws[w] = v;
    __syncthreads();
    if (t == 0) { int r = 0; for (int i = 0; i < 4; ++i) { int x = ws[i]; ws[i] = r; r += x; } }
    __syncthreads();
    int pre = bb + ws[w] + v - deg;
    npre[t] = pre; ncur[t] = 0;
    __syncthreads();
    for (int e = bb + t; e < be; e += 256) {
        unsigned p = binned[e];
        int l = p & mask;
        int r = atomicAdd(&ncur[l], 1);
        csr_src[npre[l] + r] = (int)(p >> shift);
    }
    if (t < npb) {
        int node = node0 + t;
        offsets[node] = pre;
        dinv[node] = rsqrtf((float)(deg + 1));
    }
}

// ---------------- weight prep: Wf = W1@encW (f32), bf = W1@encb; cvt all to bf16 ----------------
__global__ __launch_bounds__(128) void prep_weights_kernel(const float* __restrict__ W1,
                                                           const float* __restrict__ encW,
                                                           const float* __restrict__ encb,
                                                           const float* __restrict__ W2,
                                                           const float* __restrict__ decW,
                                                           __hip_bfloat16* __restrict__ Wfb,
                                                           float* __restrict__ bff,
                                                           __hip_bfloat16* __restrict__ W2b,
                                                           __hip_bfloat16* __restrict__ decWb) {
    int i = blockIdx.x;
    int j = threadIdx.x;
    const float* w1r = W1 + (size_t)i * 128;
    float s0 = 0.f, s1 = 0.f, s2 = 0.f, s3 = 0.f;
    for (int k = 0; k < 128; k += 4) {
        s0 += w1r[k + 0] * encW[(size_t)(k + 0) * 128 + j];
        s1 += w1r[k + 1] * encW[(size_t)(k + 1) * 128 + j];
        s2 += w1r[k + 2] * encW[(size_t)(k + 2) * 128 + j];
        s3 += w1r[k + 3] * encW[(size_t)(k + 3) * 128 + j];
    }
    Wfb[(size_t)i * 128 + j] = __float2bfloat16((s0 + s1) + (s2 + s3));
    W2b[(size_t)i * 128 + j] = __float2bfloat16(W2[(size_t)i * 128 + j]);
    if (i < 48) decWb[(size_t)i * 128 + j] = __float2bfloat16(i < 40 ? decW[(size_t)i * 128 + j] : 0.f);
    float t = w1r[j] * encb[j];
#pragma unroll
    for (int o = 32; o; o >>= 1) t += __shfl_down(t, o);
    __shared__ float red[2];
    if ((j & 63) == 0) red[j >> 6] = t;
    __syncthreads();
    if (j == 0) bff[i] = red[0] + red[1];
}

__device__ inline bf16x8 cvt8(float4 lo, float4 hi) {
    union { unsigned short u[8]; bf16x8 v; } t;
    t.u[0] = __builtin_bit_cast(unsigned short, __float2bfloat16(lo.x));
    t.u[1] = __builtin_bit_cast(unsigned short, __float2bfloat16(lo.y));
    t.u[2] = __builtin_bit_cast(unsigned short, __float2bfloat16(lo.z));
    t.u[3] = __builtin_bit_cast(unsigned short, __float2bfloat16(lo.w));
    t.u[4] = __builtin_bit_cast(unsigned short, __float2bfloat16(hi.x));
    t.u[5] = __builtin_bit_cast(unsigned short, __float2bfloat16(hi.y));
    t.u[6] = __builtin_bit_cast(unsigned short, __float2bfloat16(hi.z));
    t.u[7] = __builtin_bit_cast(unsigned short, __float2bfloat16(hi.w));
    return t.v;
}

// ---------------- encoder GEMM: hb = dinv[r]*(X @ Wf^T + bf), row-major bf16 out ----------------
__global__ __launch_bounds__(256) void gemm_enc_kernel(const float* __restrict__ Ain,
                                                       const __hip_bfloat16* __restrict__ W,
                                                       const float* __restrict__ bias,
                                                       const float* __restrict__ dscale,
                                                       __hip_bfloat16* __restrict__ out, int M) {
    int lane = threadIdx.x & 63;
    int wave = threadIdx.x >> 6;
    int row0 = blockIdx.x * 128 + wave * 32;
    int kgrp = lane >> 4, cl = lane & 15;

    bf16x8 afrag[2][4];
#pragma unroll
    for (int rt = 0; rt < 2; ++rt) {
        int ar = row0 + rt * 16 + cl;
        if (ar >= M) ar = M - 1;
        const float* Ar = Ain + (size_t)ar * 128;
#pragma unroll
        for (int c = 0; c < 4; ++c) {
            const float4* q = reinterpret_cast<const float4*>(Ar + (4 * c + kgrp) * 8);
            afrag[rt][c] = cvt8(q[0], q[1]);
        }
    }

    f32x4 acc[2][8];
#pragma unroll
    for (int rt = 0; rt < 2; ++rt)
#pragma unroll
        for (int t = 0; t < 8; ++t) acc[rt][t] = {0.f, 0.f, 0.f, 0.f};

#pragma unroll
    for (int c = 0; c < 4; ++c) {
#pragma unroll
        for (int t = 0; t < 8; ++t) {
            bf16x8 bfrag = reinterpret_cast<const bf16x8*>(W + (size_t)(t * 16 + cl) * 128)[4 * c + kgrp];
            acc[0][t] = __builtin_amdgcn_mfma_f32_16x16x32_bf16(afrag[0][c], bfrag, acc[0][t], 0, 0, 0);
            acc[1][t] = __builtin_amdgcn_mfma_f32_16x16x32_bf16(afrag[1][c], bfrag, acc[1][t], 0, 0, 0);
        }
    }

#pragma unroll
    for (int rt = 0; rt < 2; ++rt) {
        int rbase = row0 + rt * 16 + kgrp * 4;
#pragma unroll
        for (int i = 0; i < 4; ++i) {
            int r = rbase + i;
            float sc = dscale[(r < M) ? r : (M - 1)];
#pragma unroll
            for (int t = 0; t < 8; ++t) {
                int col = t * 16 + cl;
                float v = (acc[rt][t][i] + bias[col]) * sc;
                unsigned int uv = __builtin_bit_cast(unsigned short, __float2bfloat16(v));
                unsigned int pv = (unsigned int)__shfl_xor((int)uv, 1);
                if (!(lane & 1) && r < M)
                    *reinterpret_cast<unsigned int*>(out + (size_t)r * 128 + col) = (uv & 0xffffu) | (pv << 16);
            }
        }
    }
}

// ---------------- pipelined agg phase: 16-node tile, 4 waves x NPW=4 ----------------
// csr padded with >=8 zero entries past E. All NPW self-rows + first csr batches
// issue in the prologue; node i+1's 8 row-loads issue before node i's accumulation.
// LDS u32 index: row*64 + (lane ^ ((row&15)<<2))
template<int NPW>
__device__ __forceinline__ void agg_phase(const __hip_bfloat16* __restrict__ h,
                                          const int* __restrict__ csr,
                                          const int* __restrict__ offsets,
                                          const float* __restrict__ dinv,
                                          const float* __restrict__ bias,
                                          unsigned* lds, int tile0, int N) {
    int w = threadIdx.x >> 6, lane = threadIdx.x & 63;
    int bc = lane * 2;
    float2 bb = *reinterpret_cast<const float2*>(&bias[bc]);
    int base = tile0 + w * NPW;
    int oidx = base + (lane < NPW ? lane : NPW);
    if (oidx > N) oidx = N;
    int off = offsets[oidx];                     // one coalesced load

    int j0a[NPW], dga[NPW], nda[NPW];
    unsigned qs[NPW];
#pragma unroll
    for (int i = 0; i < NPW; ++i) {
        int node = base + i;
        nda[i] = __builtin_amdgcn_readfirstlane((node < N) ? node : (N - 1));
        j0a[i] = __builtin_amdgcn_readfirstlane(__shfl(off, i));
        int j1 = __builtin_amdgcn_readfirstlane(__shfl(off, i + 1));
        dga[i] = j1 - j0a[i];                    // 0 for dead nodes
        qs[i] = *reinterpret_cast<const unsigned*>(&h[(size_t)nda[i] * 128 + bc]);  // self row
    }
    // prefetch first csr batch of every node (uniform -> s_loads; pad makes it safe)
    int sc[NPW][8];
#pragma unroll
    for (int i = 0; i < NPW; ++i)
#pragma unroll
        for (int k = 0; k < 8; ++k)
            sc[i][k] = csr[j0a[i] + k];
    // prime node 0's first-batch row loads
    unsigned qn[8];
#pragma unroll
    for (int k = 0; k < 8; ++k)
        qn[k] = *reinterpret_cast<const unsigned*>(&h[(size_t)sc[0][k] * 128 + bc]);

#pragma unroll
    for (int i = 0; i < NPW; ++i) {
        int j0 = j0a[i], dg = dga[i];
        bool live = (base + i) < N;

        unsigned qc[8];
#pragma unroll
        for (int k = 0; k < 8; ++k) qc[k] = qn[k];
        if (i + 1 < NPW) {                       // issue next node's first batch NOW
#pragma unroll
            for (int k = 0; k < 8; ++k)
                qn[k] = *reinterpret_cast<const unsigned*>(&h[(size_t)sc[i + 1][k] * 128 + bc]);
        }

        float ax[8], ay[8];
        ax[0] = __builtin_bit_cast(float, qs[i] << 16);
        ay[0] = __builtin_bit_cast(float, qs[i] & 0xffff0000u);
#pragma unroll
        for (int k = 1; k < 8; ++k) { ax[k] = 0.f; ay[k] = 0.f; }

        // batch 0 (masked; dg uniform)
#pragma unroll
        for (int k = 0; k < 8; ++k) {
            unsigned q = (k < dg) ? qc[k] : 0u;
            ax[k] += __builtin_bit_cast(float, q << 16);
            ay[k] += __builtin_bit_cast(float, q & 0xffff0000u);
        }
        // batches 1..nb-1
        int nb = (dg + 7) >> 3;
        for (int b = 1; b < nb; ++b) {
            int jb = j0 + 8 * b;
            int s[8];
#pragma unroll
            for (int k = 0; k < 8; ++k) s[k] = csr[jb + k];
            unsigned q[8];
#pragma unroll
            for (int k = 0; k < 8; ++k)
                q[k] = *reinterpret_cast<const unsigned*>(&h[(size_t)s[k] * 128 + bc]);
            int rem = dg - 8 * b;
#pragma unroll
            for (int k = 0; k < 8; ++k) {
                unsigned qq = (k < rem) ? q[k] : 0u;
                ax[k] += __builtin_bit_cast(float, qq << 16);
                ay[k] += __builtin_bit_cast(float, qq & 0xffff0000u);
            }
        }

        float sx = ((ax[0] + ax[1]) + (ax[2] + ax[3])) + ((ax[4] + ax[5]) + (ax[6] + ax[7]));
        float sy = ((ay[0] + ay[1]) + (ay[2] + ay[3])) + ((ay[4] + ay[5]) + (ay[6] + ay[7]));
        float dd = dinv[nda[i]];
        float ox = fmaxf(dd * sx + bb.x, 0.f);
        float oy = fmaxf(dd * sy + bb.y, 0.f);
        unsigned ow = (unsigned)__builtin_bit_cast(unsigned short, __float2bfloat16(ox)) |
                      ((unsigned)__builtin_bit_cast(unsigned short, __float2bfloat16(oy)) << 16);
        if (!live) ow = 0u;
        int row = w * NPW + i;
        lds[row * 64 + (lane ^ ((row & 15) << 2))] = ow;
    }
}

// ---------------- fused agg1 + conv2 GEMM (16-node tile, 4 waves) ----------------
// GEMM tail: wave w -> col-quarter w (16 distinct rows, 32 cols, 8 MFMA).
__global__ __launch_bounds__(256, 8) void agg_gemm_kernel(const __hip_bfloat16* __restrict__ h,
                                                          const int* __restrict__ csr,
                                                          const int* __restrict__ offsets,
                                                          const float* __restrict__ dinv,
                                                          const float* __restrict__ bias,
                                                          const __hip_bfloat16* __restrict__ W,
                                                          __hip_bfloat16* __restrict__ out, int N) {
    __shared__ unsigned lds[16 * 64];
    int tile0 = blockIdx.x * 16;
    agg_phase<4>(h, csr, offsets, dinv, bias, lds, tile0, N);
    __syncthreads();

    int lane = threadIdx.x & 63, w = threadIdx.x >> 6;
    int kgrp = lane >> 4, cl = lane & 15;
    int cq = w;                                   // col-quarter 0..3
    bf16x8 afrag[4];
#pragma unroll
    for (int c = 0; c < 4; ++c) {
        int kk = 4 * c + kgrp;
        afrag[c] = *reinterpret_cast<const bf16x8*>(&lds[cl * 64 + ((kk * 4) ^ (cl << 2))]);
    }
    f32x4 acc[2];
#pragma unroll
    for (int t = 0; t < 2; ++t) acc[t] = {0.f, 0.f, 0.f, 0.f};
#pragma unroll
    for (int c = 0; c < 4; ++c)
#pragma unroll
        for (int t = 0; t < 2; ++t) {
            bf16x8 bfrag = reinterpret_cast<const bf16x8*>(W + (size_t)(cq * 32 + t * 16 + cl) * 128)[4 * c + kgrp];
            acc[t] = __builtin_amdgcn_mfma_f32_16x16x32_bf16(afrag[c], bfrag, acc[t], 0, 0, 0);
        }
#pragma unroll
    for (int i = 0; i < 4; ++i) {
        int r = tile0 + kgrp * 4 + i;
        float sc = dinv[(r < N) ? r : (N - 1)];
#pragma unroll
        for (int t = 0; t < 2; ++t) {
            int col = cq * 32 + t * 16 + cl;
            float v = acc[t][i] * sc;
            unsigned uv = __builtin_bit_cast(unsigned short, __float2bfloat16(v));
            unsigned pv = (unsigned)__shfl_xor((int)uv, 1);
            if (!(lane & 1) && r < N)
                *reinterpret_cast<unsigned*>(out + (size_t)r * 128 + col) = (uv & 0xffffu) | (pv << 16);
        }
    }
}

// ---------------- fused agg2 + decoder GEMM + log_softmax (16-node tile, 4 waves) ----------------
// Wave 0 computes all 3 col-tiles (full rows) so softmax stays in-wave; waves 1-3 exit.
__global__ __launch_bounds__(256, 8) void agg_dec_kernel(const __hip_bfloat16* __restrict__ h,
                                                         const int* __restrict__ csr,
                                                         const int* __restrict__ offsets,
                                                         const float* __restrict__ dinv,
                                                         const float* __restrict__ bias,
                                                         const __hip_bfloat16* __restrict__ Wd,
                                                         const float* __restrict__ bd,
                                                         float* __restrict__ out, int N) {
    __shared__ unsigned lds[16 * 64];
    int tile0 = blockIdx.x * 16;
    agg_phase<4>(h, csr, offsets, dinv, bias, lds, tile0, N);
    __syncthreads();

    int lane = threadIdx.x & 63, w = threadIdx.x >> 6;
    if (w != 0) return;
    int kgrp = lane >> 4, cl = lane & 15;
    bf16x8 afrag[4];
#pragma unroll
    for (int c = 0; c < 4; ++c) {
        int kk = 4 * c + kgrp;
        afrag[c] = *reinterpret_cast<const bf16x8*>(&lds[cl * 64 + ((kk * 4) ^ (cl << 2))]);
    }
    f32x4 acc[3];
#pragma unroll
    for (int t = 0; t < 3; ++t) acc[t] = {0.f, 0.f, 0.f, 0.f};
#pragma unroll
    for (int c = 0; c < 4; ++c)
#pragma unroll
        for (int t = 0; t < 3; ++t) {
            bf16x8 bfrag = reinterpret_cast<const bf16x8*>(Wd + (size_t)(t * 16 + cl) * 128)[4 * c + kgrp];
            acc[t] = __builtin_amdgcn_mfma_f32_16x16x32_bf16(afrag[c], bfrag, acc[t], 0, 0, 0);
        }

    float v[3][4];
#pragma unroll
    for (int t = 0; t < 3; ++t) {
        int col = t * 16 + cl;
        float bv = (col < 40) ? bd[col] : 0.f;
#pragma unroll
        for (int i = 0; i < 4; ++i)
            v[t][i] = (col < 40) ? (acc[t][i] + bv) : -INFINITY;
    }
#pragma unroll
    for (int i = 0; i < 4; ++i) {
        float m = fmaxf(fmaxf(v[0][i], v[1][i]), v[2][i]);
#pragma unroll
        for (int o = 1; o < 16; o <<= 1) m = fmaxf(m, __shfl_xor(m, o));
        float s = 0.f;
#pragma unroll
        for (int t = 0; t < 3; ++t) s += (v[t][i] > -INFINITY) ? __expf(v[t][i] - m) : 0.f;
#pragma unroll
        for (int o = 1; o < 16; o <<= 1) s += __shfl_xor(s, o);
        float lse = __logf(s);
        int r = tile0 + kgrp * 4 + i;
        if (r < N) {
#pragma unroll
            for (int t = 0; t < 3; ++t) {
                int col = t * 16 + cl;
                if (col < 40) out[(size_t)r * 40 + col] = v[t][i] - m - lse;
            }
        }
    }
}

extern "C" void kernel_launch(void* const* d_in, const int* in_sizes, int n_in,
                              void* d_out, int out_size, void* d_ws, size_t ws_size,
                              hipStream_t stream) {
    const float* X    = (const float*)d_in[0];
    const int*   ei   = (const int*)d_in[1];
    const float* encW = (const float*)d_in[2];
    const float* encb = (const float*)d_in[3];
    const float* W1   = (const float*)d_in[4];
    const float* b1   = (const float*)d_in[5];
    const float* W2   = (const float*)d_in[6];
    const float* b2   = (const float*)d_in[7];
    const float* decW = (const float*)d_in[8];
    const float* decb = (const float*)d_in[9];

    const int N = in_sizes[0] / 128;
    const int E = in_sizes[1] / 2;
    const int* src = ei;
    const int* dst = ei + E;

    int shift = 7;
    while ((((N - 1) >> shift) + 1) > 1024) ++shift;
    const int NBK = ((N - 1) >> shift) + 1;

    uint8_t* p = (uint8_t*)d_ws;
    auto carve = [&](size_t bytes) -> void* {
        uint8_t* r = p;
        p += (bytes + 255) & ~(size_t)255;
        return (void*)r;
    };
    int*   offsets = (int*)carve((size_t)(N + 1) * 4);
    float* dinv    = (float*)carve((size_t)N * 4);
    int*   bhist   = (int*)carve(1025 * 4);
    int*   bbase   = (int*)carve(1025 * 4);
    int*   bcur    = (int*)carve(1024 * 4);
    int*   csr_src = (int*)carve(((size_t)E + 16) * 4);  // zero pad for batch prefetch
    __hip_bfloat16* Wfb   = (__hip_bfloat16*)carve(16384 * 2);
    __hip_bfloat16* W2b   = (__hip_bfloat16*)carve(16384 * 2);
    __hip_bfloat16* decWb = (__hip_bfloat16*)carve(48 * 128 * 2);
    float*          bff   = (float*)carve(128 * 4);
    __hip_bfloat16* xb    = (__hip_bfloat16*)carve((size_t)N * 128 * 2);
    __hip_bfloat16* hb    = (__hip_bfloat16*)carve((size_t)N * 128 * 2);
    unsigned* binned = (unsigned*)xb;   // dead before xb is first written (by agg_gemm)

    // --- weight prep (independent of graph) ---
    prep_weights_kernel<<<128, 128, 0, stream>>>(W1, encW, encb, W2, decW, Wfb, bff, W2b, decWb);

    // --- graph structure ---
    hipMemsetAsync(bhist, 0, (size_t)NBK * 4, stream);
    hipMemsetAsync(csr_src + E, 0, 16 * 4, stream);      // zero the prefetch pad
    bucket_hist_kernel<<<(E + 4095) / 4096, 256, 0, stream>>>(dst, bhist, E, NBK, shift);
    bucket_scan_kernel<<<1, 256, 0, stream>>>(bhist, bbase, bcur, NBK, &offsets[N], E);
    bin_edges_kernel<<<(E + 8191) / 8192, 256, 0, stream>>>(src, dst, bcur, binned, E, NBK, shift);
    bucket_build_kernel<<<NBK, 256, 0, stream>>>(binned, bbase, csr_src, offsets, dinv, N, shift);

    int gblocks = (N + 127) / 128;
    int tblocks = (N + 15) / 16;
    // fused encoder+conv1 linear: hb = dinv[r] * (X @ Wf^T + bf)
    gemm_enc_kernel<<<gblocks, 256, 0, stream>>>(X, Wfb, bff, dinv, hb, N);
    // agg1 (+b1, relu) fused with conv2 linear: xb = dinv[r] * (agg(hb) @ W2^T)
    agg_gemm_kernel<<<tblocks, 256, 0, stream>>>(hb, csr_src, offsets, dinv, b1, W2b, xb, N);
    // agg2 (+b2, relu) fused with decoder + log_softmax
    agg_dec_kernel<<<tblocks, 256, 0, stream>>>(xb, csr_src, offsets, dinv, b2, decWb, decb,
                                                (float*)d_out, N);
}